// Round 1
// baseline (31576.035 us; speedup 1.0000x reference)
//
#include <hip/hip_runtime.h>
#include <cstddef>

typedef _Float16 f16;
typedef _Float16 f16x8 __attribute__((ext_vector_type(8)));
typedef _Float16 f16x4 __attribute__((ext_vector_type(4)));
typedef float f32x4 __attribute__((ext_vector_type(4)));

#define T_STEPS 512
#define BATCH   64
#define DD      1024
#define NTOT    4096   // 4 gates * D, n = d*4 + g (g: 0=i,1=f,2=c,3=o)
#define M_TOT   (T_STEPS * BATCH)   // 32768

// ---- workspace layout (bytes), all 4 KiB aligned ----
#define OFF_CTR   0ull
#define OFF_HBUF  4096ull                          // 2 * 64 * 1024 f16 = 262144 B
#define OFF_BIAS  (OFF_HBUF + 262144ull)           // 4096 f32 = 16384 B
#define OFF_WHP   (OFF_BIAS + 16384ull)            // 256*32*64*8 f16 = 8 MB
#define OFF_BXP   (OFF_WHP + 8388608ull)           // 8 MB
#define OFF_XW    (OFF_BXP + 8388608ull)           // 32768*4096 f16 = 256 MB
// total needed = OFF_XW + 268435456 = ~273 MB

__device__ __forceinline__ float sigm(float x) { return 1.f / (1.f + __expf(-x)); }
__device__ __forceinline__ float tanh_fast(float x) {
    float e = __expf(-2.f * fabsf(x));
    float t = (1.f - e) / (1.f + e);
    return x >= 0.f ? t : -t;
}

// ---------------------------------------------------------------------------
// Prepack: weight gather -> f16 fragment-order layouts, bias gather, hbuf init,
// barrier counter zero. Fragment layout for mfma_f32_16x16x32_f16 B-operand:
// lane l holds B[k = S*32 + (l>>4)*8 + jj][n = NT*16 + (l&15)], stored as
// arr[((NT*32 + S)*64 + l)*8 + jj].
// ---------------------------------------------------------------------------
__global__ void prepack_kernel(const float* __restrict__ Wi, const float* __restrict__ Wf,
                               const float* __restrict__ Wc, const float* __restrict__ Wo,
                               const float* __restrict__ bi, const float* __restrict__ bf,
                               const float* __restrict__ bc, const float* __restrict__ bo,
                               const float* __restrict__ c0,
                               f16* __restrict__ whp, f16* __restrict__ bxp,
                               float* __restrict__ biasp, f16* __restrict__ hbuf,
                               unsigned int* __restrict__ ctr)
{
    unsigned int gid = blockIdx.x * 256u + threadIdx.x;
    if (gid == 0) *ctr = 0u;
    const float* Ww[4] = {Wi, Wf, Wc, Wo};
    if (gid < 8388608u) {
        unsigned int hi = (gid >= 4194304u);      // 0 -> bxp (k 0..1023), 1 -> whp (k 1024..2047)
        unsigned int e  = gid & 4194303u;
        unsigned int jj = e & 7u;
        unsigned int lidx = (e >> 3) & 63u;
        unsigned int S  = (e >> 9) & 31u;
        unsigned int NT = e >> 14;
        unsigned int n  = NT * 16u + (lidx & 15u);
        unsigned int k  = S * 32u + (lidx >> 4) * 8u + jj + (hi ? 1024u : 0u);
        unsigned int g  = n & 3u, d = n >> 2;
        float v = Ww[g][k * 1024u + d];
        (hi ? whp : bxp)[e] = (f16)v;
    } else if (gid < 8392704u) {                  // bias: 4096
        unsigned int n = gid - 8388608u;
        const float* Bb[4] = {bi, bf, bc, bo};
        biasp[n] = Bb[n & 3u][n >> 2];
    } else if (gid < 8458240u) {                  // hbuf[0][b][d] = tanh(c0[d]) : 65536
        unsigned int e2 = gid - 8392704u;
        hbuf[e2] = (f16)tanh_fast(c0[e2 & 1023u]);
    }
}

// ---------------------------------------------------------------------------
// Phase 1: xw[m][n] = batch[m][:1024] @ Wx[:, n] + bias[n]   (f16 out)
// m = t*64 + b, n = d*4 + g. 128x128 tile per block, 4 waves x (2 M-tiles,
// 8 N-tiles), K = 1024 in 32 slices of 32. B-frags straight from prepacked
// global (fragment order, 16 B/lane).
// ---------------------------------------------------------------------------
__global__ __launch_bounds__(256) void gemm_x_kernel(
    const float* __restrict__ A, const f16* __restrict__ Bp,
    const float* __restrict__ biasp, f16* __restrict__ xw)
{
    const int tid = threadIdx.x;
    const int w = tid >> 6, l = tid & 63;
    const int lr = l & 15, lq = l >> 4;
    const int n0 = blockIdx.x * 128;   // fast-varying -> consecutive blocks share A rows (L2)
    const int m0 = blockIdx.y * 128;

    f32x4 acc[2][8];
#pragma unroll
    for (int mt = 0; mt < 2; mt++)
#pragma unroll
        for (int nt = 0; nt < 8; nt++) acc[mt][nt] = (f32x4){0.f, 0.f, 0.f, 0.f};

    const float* a0 = A + (size_t)(m0 + 32 * w + lr) * 1024 + lq * 8;
    const f16x8* bp = (const f16x8*)Bp + (size_t)(n0 >> 4) * (32 * 64) + l;

#pragma unroll 2
    for (int s = 0; s < 32; s++) {
        f16x8 af[2];
#pragma unroll
        for (int mt = 0; mt < 2; mt++) {
            const float* ap = a0 + mt * (16 * 1024) + 32 * s;
            float4 v0 = *(const float4*)ap;
            float4 v1 = *(const float4*)(ap + 4);
            f16x8 tt;
            tt[0] = (f16)v0.x; tt[1] = (f16)v0.y; tt[2] = (f16)v0.z; tt[3] = (f16)v0.w;
            tt[4] = (f16)v1.x; tt[5] = (f16)v1.y; tt[6] = (f16)v1.z; tt[7] = (f16)v1.w;
            af[mt] = tt;
        }
#pragma unroll
        for (int nt = 0; nt < 8; nt++) {
            f16x8 bfr = bp[(size_t)(nt * 32 + s) * 64];
            acc[0][nt] = __builtin_amdgcn_mfma_f32_16x16x32_f16(af[0], bfr, acc[0][nt], 0, 0, 0);
            acc[1][nt] = __builtin_amdgcn_mfma_f32_16x16x32_f16(af[1], bfr, acc[1][nt], 0, 0, 0);
        }
    }
    // epilogue: D lane map col = l&15, row = (l>>4)*4 + r
#pragma unroll
    for (int nt = 0; nt < 8; nt++) {
        int n = n0 + nt * 16 + lr;
        float bias = biasp[n];
#pragma unroll
        for (int mt = 0; mt < 2; mt++) {
#pragma unroll
            for (int r = 0; r < 4; r++) {
                int m = m0 + 32 * w + mt * 16 + lq * 4 + r;
                xw[(size_t)m * NTOT + n] = (f16)(acc[mt][nt][r] + bias);
            }
        }
    }
}

// ---------------------------------------------------------------------------
// Phase 2: persistent recurrent kernel. 256 WGs x 256 thr. WG j owns output
// dims d in [4j, 4j+4) == gate columns n in [16j, 16j+16). Recurrent weights
// in VGPRs (32 x f16x8). h ping-pongs in global (f16 [2][64][1024]); one
// grid-wide spin barrier per step (counter monotonic to 256*512).
// ---------------------------------------------------------------------------
__global__ __launch_bounds__(256, 1) void lstm_persist_kernel(
    const f16* __restrict__ xw, const f16* __restrict__ whp,
    const int* __restrict__ lengths, const float* __restrict__ c0,
    float* __restrict__ out, f16* hbuf, unsigned int* ctr)
{
    const int j = blockIdx.x;
    const int tid = threadIdx.x;
    const int w = tid >> 6, l = tid & 63;
    const int lr = l & 15, lq = l >> 4;

    // K=1024 -> 32 slices, fragment order: frag index = (j*32 + s)*64 + l
    f16x8 wfrag[32];
    const f16x8* wp = (const f16x8*)whp + (size_t)j * (32 * 64) + l;
#pragma unroll
    for (int s = 0; s < 32; s++) wfrag[s] = wp[s * 64];

    const int b = tid >> 2, dl = tid & 3;     // this thread's (batch, local dim)
    float c = c0[4 * j + dl];
    const int len = lengths[b];

    const int rowA = 16 * w + lr;             // wave w computes batch rows [16w,16w+16)
    const int koff = lq * 8;

    __shared__ float pre_lds[64 * 16];

    for (int t = 0; t < T_STEPS; t++) {
        const int p = t & 1;
        const f16* hb = hbuf + p * (BATCH * DD);
        const f16x8* ap = (const f16x8*)(hb + (size_t)rowA * DD + koff);

        // prefetch this thread's x-part gate values (independent of MFMA loop)
        const f16* xwp = xw + (size_t)(t * BATCH + b) * NTOT + 16 * j + 4 * dl;
        f16x4 xg = *(const f16x4*)xwp;

        f32x4 acc0 = {0.f, 0.f, 0.f, 0.f}, acc1 = {0.f, 0.f, 0.f, 0.f};
#pragma unroll
        for (int s = 0; s < 32; s += 2) {
            acc0 = __builtin_amdgcn_mfma_f32_16x16x32_f16(ap[4 * s],       wfrag[s],     acc0, 0, 0, 0);
            acc1 = __builtin_amdgcn_mfma_f32_16x16x32_f16(ap[4 * (s + 1)], wfrag[s + 1], acc1, 0, 0, 0);
        }
        f32x4 pre = acc0 + acc1;
        // D layout: row = 16w + lq*4 + r (batch), col = lr (n_local)
#pragma unroll
        for (int r = 0; r < 4; r++)
            pre_lds[(16 * w + lq * 4 + r) * 16 + lr] = pre[r];
        __syncthreads();

        float4 g4 = *(const float4*)&pre_lds[b * 16 + 4 * dl];
        float pi = g4.x + (float)xg[0];
        float pf = g4.y + (float)xg[1];
        float pg = g4.z + (float)xg[2];
        float po = g4.w + (float)xg[3];
        float iv = sigm(pi), fv = sigm(pf), gv = tanh_fast(pg), ov = sigm(po);
        c = fv * c + iv * gv;
        float h = ov * tanh_fast(c);
        if (t >= len) h = 0.f;                // mask carried AND emitted h (ref semantics)
        out[(size_t)t * (BATCH * DD) + (size_t)b * DD + 4 * j + dl] = h;
        hbuf[(size_t)(p ^ 1) * (BATCH * DD) + (size_t)b * DD + 4 * j + dl] = (f16)h;

        // grid barrier: release (wbl2) -> arrive -> spin -> acquire (inv L2)
        __threadfence();
        __syncthreads();
        if (tid == 0) {
            __hip_atomic_fetch_add(ctr, 1u, __ATOMIC_RELAXED, __HIP_MEMORY_SCOPE_AGENT);
            const unsigned int target = 256u * (unsigned int)(t + 1);
            while (__hip_atomic_load(ctr, __ATOMIC_RELAXED, __HIP_MEMORY_SCOPE_AGENT) < target)
                __builtin_amdgcn_s_sleep(1);
        }
        __syncthreads();
        __threadfence();
    }
}

// ---------------------------------------------------------------------------
extern "C" void kernel_launch(void* const* d_in, const int* in_sizes, int n_in,
                              void* d_out, int out_size, void* d_ws, size_t ws_size,
                              hipStream_t stream) {
    const float* batch   = (const float*)d_in[0];
    const int*   lengths = (const int*)d_in[1];
    const float* c0      = (const float*)d_in[2];
    const float* Wi = (const float*)d_in[3];
    const float* bi = (const float*)d_in[4];
    const float* Wf = (const float*)d_in[5];
    const float* bf = (const float*)d_in[6];
    const float* Wc = (const float*)d_in[7];
    const float* bc = (const float*)d_in[8];
    const float* Wo = (const float*)d_in[9];
    const float* bo = (const float*)d_in[10];
    float* out = (float*)d_out;

    char* ws = (char*)d_ws;
    unsigned int* ctr = (unsigned int*)(ws + OFF_CTR);
    f16*   hbuf  = (f16*)(ws + OFF_HBUF);
    float* biasp = (float*)(ws + OFF_BIAS);
    f16*   whp   = (f16*)(ws + OFF_WHP);
    f16*   bxp   = (f16*)(ws + OFF_BXP);
    f16*   xw    = (f16*)(ws + OFF_XW);

    prepack_kernel<<<33040, 256, 0, stream>>>(Wi, Wf, Wc, Wo, bi, bf, bc, bo, c0,
                                              whp, bxp, biasp, hbuf, ctr);
    gemm_x_kernel<<<dim3(32, 256), 256, 0, stream>>>(batch, bxp, biasp, xw);
    lstm_persist_kernel<<<256, 256, 0, stream>>>(xw, whp, lengths, c0, out, hbuf, ctr);
}

// Round 2
// 10968.714 us; speedup vs baseline: 2.8787x; 2.8787x over previous
//
#include <hip/hip_runtime.h>
#include <cstddef>

typedef _Float16 f16;
typedef _Float16 f16x8 __attribute__((ext_vector_type(8)));
typedef _Float16 f16x4 __attribute__((ext_vector_type(4)));
typedef float f32x4 __attribute__((ext_vector_type(4)));

#define T_STEPS 512
#define BATCH   64
#define DD      1024
#define NTOT    4096   // 4 gates * D, n = d*4 + g (g: 0=i,1=f,2=c,3=o)

// ---- workspace layout (bytes), all 4 KiB aligned ----
#define OFF_FLAGS 0ull                             // 256 u32 = 1 KiB (barrier epochs)
#define OFF_HBUF  4096ull                          // 2 * 64 * 1024 f16 = 262144 B
#define OFF_BIAS  (OFF_HBUF + 262144ull)           // 4096 f32 = 16384 B
#define OFF_WHP   (OFF_BIAS + 16384ull)            // 8 MB
#define OFF_BXP   (OFF_WHP + 8388608ull)           // 8 MB
#define OFF_XW    (OFF_BXP + 8388608ull)           // 32768*4096 f16 = 256 MB

__device__ __forceinline__ float sigm(float x) { return 1.f / (1.f + __expf(-x)); }
__device__ __forceinline__ float tanh_fast(float x) {
    float e = __expf(-2.f * fabsf(x));
    float t = (1.f - e) / (1.f + e);
    return x >= 0.f ? t : -t;
}

// coherent (cross-XCD) primitives: relaxed agent-scope atomics compile to
// sc0 sc1 loads/stores -> bypass per-XCD L2, hit the coherent IF cache.
__device__ __forceinline__ unsigned int load_coh_u32(const unsigned int* p) {
    return __hip_atomic_load((unsigned int*)p, __ATOMIC_RELAXED, __HIP_MEMORY_SCOPE_AGENT);
}
__device__ __forceinline__ void store_coh_u16(unsigned short* p, unsigned short v) {
    __hip_atomic_store(p, v, __ATOMIC_RELAXED, __HIP_MEMORY_SCOPE_AGENT);
}
__device__ __forceinline__ void store_coh_u32(unsigned int* p, unsigned int v) {
    __hip_atomic_store(p, v, __ATOMIC_RELAXED, __HIP_MEMORY_SCOPE_AGENT);
}
__device__ __forceinline__ void waitcnt_vm0() {
    asm volatile("s_waitcnt vmcnt(0)" ::: "memory");
}

// ---------------------------------------------------------------------------
// Prepack (unchanged except flags init): weights -> f16 fragment order.
// B-frag for mfma_f32_16x16x32_f16: lane l holds B[k=S*32+(l>>4)*8+jj][n=NT*16+(l&15)]
// stored at arr[((NT*32+S)*64+l)*8+jj].
// ---------------------------------------------------------------------------
__global__ void prepack_kernel(const float* __restrict__ Wi, const float* __restrict__ Wf,
                               const float* __restrict__ Wc, const float* __restrict__ Wo,
                               const float* __restrict__ bi, const float* __restrict__ bf,
                               const float* __restrict__ bc, const float* __restrict__ bo,
                               const float* __restrict__ c0,
                               f16* __restrict__ whp, f16* __restrict__ bxp,
                               float* __restrict__ biasp, f16* __restrict__ hbuf,
                               unsigned int* __restrict__ flags)
{
    unsigned int gid = blockIdx.x * 256u + threadIdx.x;
    if (gid < 256u) flags[gid] = 0u;
    const float* Ww[4] = {Wi, Wf, Wc, Wo};
    if (gid < 8388608u) {
        unsigned int hi = (gid >= 4194304u);      // 0 -> bxp (k 0..1023), 1 -> whp (k 1024..2047)
        unsigned int e  = gid & 4194303u;
        unsigned int jj = e & 7u;
        unsigned int lidx = (e >> 3) & 63u;
        unsigned int S  = (e >> 9) & 31u;
        unsigned int NT = e >> 14;
        unsigned int n  = NT * 16u + (lidx & 15u);
        unsigned int k  = S * 32u + (lidx >> 4) * 8u + jj + (hi ? 1024u : 0u);
        unsigned int g  = n & 3u, d = n >> 2;
        float v = Ww[g][k * 1024u + d];
        (hi ? whp : bxp)[e] = (f16)v;
    } else if (gid < 8392704u) {                  // bias: 4096
        unsigned int n = gid - 8388608u;
        const float* Bb[4] = {bi, bf, bc, bo};
        biasp[n] = Bb[n & 3u][n >> 2];
    } else if (gid < 8458240u) {                  // hbuf[0][b][d] = tanh(c0[d]) : 65536
        unsigned int e2 = gid - 8392704u;
        hbuf[e2] = (f16)tanh_fast(c0[e2 & 1023u]);
    }
}

// ---------------------------------------------------------------------------
// Phase 1: xw[m][n] = batch[m][:1024] @ Wx[:, n] + bias[n]   (f16 out)
// ---------------------------------------------------------------------------
__global__ __launch_bounds__(256) void gemm_x_kernel(
    const float* __restrict__ A, const f16* __restrict__ Bp,
    const float* __restrict__ biasp, f16* __restrict__ xw)
{
    const int tid = threadIdx.x;
    const int w = tid >> 6, l = tid & 63;
    const int lr = l & 15, lq = l >> 4;
    const int n0 = blockIdx.x * 128;
    const int m0 = blockIdx.y * 128;

    f32x4 acc[2][8];
#pragma unroll
    for (int mt = 0; mt < 2; mt++)
#pragma unroll
        for (int nt = 0; nt < 8; nt++) acc[mt][nt] = (f32x4){0.f, 0.f, 0.f, 0.f};

    const float* a0 = A + (size_t)(m0 + 32 * w + lr) * 1024 + lq * 8;
    const f16x8* bp = (const f16x8*)Bp + (size_t)(n0 >> 4) * (32 * 64) + l;

#pragma unroll 2
    for (int s = 0; s < 32; s++) {
        f16x8 af[2];
#pragma unroll
        for (int mt = 0; mt < 2; mt++) {
            const float* ap = a0 + mt * (16 * 1024) + 32 * s;
            float4 v0 = *(const float4*)ap;
            float4 v1 = *(const float4*)(ap + 4);
            f16x8 tt;
            tt[0] = (f16)v0.x; tt[1] = (f16)v0.y; tt[2] = (f16)v0.z; tt[3] = (f16)v0.w;
            tt[4] = (f16)v1.x; tt[5] = (f16)v1.y; tt[6] = (f16)v1.z; tt[7] = (f16)v1.w;
            af[mt] = tt;
        }
#pragma unroll
        for (int nt = 0; nt < 8; nt++) {
            f16x8 bfr = bp[(size_t)(nt * 32 + s) * 64];
            acc[0][nt] = __builtin_amdgcn_mfma_f32_16x16x32_f16(af[0], bfr, acc[0][nt], 0, 0, 0);
            acc[1][nt] = __builtin_amdgcn_mfma_f32_16x16x32_f16(af[1], bfr, acc[1][nt], 0, 0, 0);
        }
    }
#pragma unroll
    for (int nt = 0; nt < 8; nt++) {
        int n = n0 + nt * 16 + lr;
        float bias = biasp[n];
#pragma unroll
        for (int mt = 0; mt < 2; mt++) {
#pragma unroll
            for (int r = 0; r < 4; r++) {
                int m = m0 + 32 * w + mt * 16 + lq * 4 + r;
                xw[(size_t)m * NTOT + n] = (f16)(acc[mt][nt][r] + bias);
            }
        }
    }
}

// ---------------------------------------------------------------------------
// Phase 2: persistent recurrent kernel. 256 WGs x 256 thr, WG j owns dims
// [4j,4j+4). Weights (fragment order) reloaded from L2 each step (compiler's
// choice), h communicated via IF-coherent sc0sc1 loads/stores. Barrier:
// per-WG epoch flag store + all-to-all poll (no RMW, no cache fences).
// ---------------------------------------------------------------------------
__global__ __launch_bounds__(256, 1) void lstm_persist_kernel(
    const f16* __restrict__ xw, const f16* __restrict__ whp,
    const int* __restrict__ lengths, const float* __restrict__ c0,
    float* __restrict__ out, f16* hbuf, unsigned int* flags)
{
    const int j = blockIdx.x;
    const int tid = threadIdx.x;
    const int w = tid >> 6, l = tid & 63;
    const int lr = l & 15, lq = l >> 4;

    f16x8 wfrag[32];
    const f16x8* wp = (const f16x8*)whp + (size_t)j * (32 * 64) + l;
#pragma unroll
    for (int s = 0; s < 32; s++) wfrag[s] = wp[s * 64];

    const int b = tid >> 2, dl = tid & 3;
    float c = c0[4 * j + dl];
    const int len = lengths[b];

    const int rowA = 16 * w + lr;
    const int koff = lq * 8;

    __shared__ float pre_lds[64 * 16];

    for (int t = 0; t < T_STEPS; t++) {
        const int p = t & 1;
        const f16* hb = hbuf + (size_t)p * (BATCH * DD);
        const unsigned int* hb32 = (const unsigned int*)(hb + (size_t)rowA * DD + koff);

        const f16* xwp = xw + (size_t)(t * BATCH + b) * NTOT + 16 * j + 4 * dl;
        f16x4 xg = *(const f16x4*)xwp;

        f32x4 acc0 = {0.f, 0.f, 0.f, 0.f}, acc1 = {0.f, 0.f, 0.f, 0.f};
#pragma unroll
        for (int s = 0; s < 32; s += 2) {
            union { unsigned int u[4]; f16x8 v; } a0, a1;
#pragma unroll
            for (int q = 0; q < 4; q++) a0.u[q] = load_coh_u32(hb32 + 16 * s + q);
#pragma unroll
            for (int q = 0; q < 4; q++) a1.u[q] = load_coh_u32(hb32 + 16 * (s + 1) + q);
            acc0 = __builtin_amdgcn_mfma_f32_16x16x32_f16(a0.v, wfrag[s],     acc0, 0, 0, 0);
            acc1 = __builtin_amdgcn_mfma_f32_16x16x32_f16(a1.v, wfrag[s + 1], acc1, 0, 0, 0);
        }
        f32x4 pre = acc0 + acc1;
        // D layout: row = 16w + lq*4 + r (batch), col = lr (n_local)
#pragma unroll
        for (int r = 0; r < 4; r++)
            pre_lds[(16 * w + lq * 4 + r) * 16 + lr] = pre[r];
        __syncthreads();

        float4 g4 = *(const float4*)&pre_lds[b * 16 + 4 * dl];
        float pi = g4.x + (float)xg[0];
        float pf = g4.y + (float)xg[1];
        float pg = g4.z + (float)xg[2];
        float po = g4.w + (float)xg[3];
        float iv = sigm(pi), fv = sigm(pf), gv = tanh_fast(pg), ov = sigm(po);
        c = fv * c + iv * gv;
        float h = ov * tanh_fast(c);
        if (t >= len) h = 0.f;                // mask carried AND emitted h (ref semantics)

        out[(size_t)t * (BATCH * DD) + (size_t)b * DD + 4 * j + dl] = h;

        if (t + 1 < T_STEPS) {
            // write-through h for next step (visible at IF, no fence needed)
            f16 hf = (f16)h;
            store_coh_u16((unsigned short*)(hbuf + (size_t)(p ^ 1) * (BATCH * DD)
                                            + (size_t)b * DD + 4 * j + dl),
                          __builtin_bit_cast(unsigned short, hf));
            waitcnt_vm0();                    // per-wave: h stores reached coherency point
            __syncthreads();                  // whole WG done storing
            if (tid == 0) store_coh_u32(&flags[j], (unsigned int)(t + 1));
            // all-to-all poll: thread i watches WG i's epoch
            const unsigned int want = (unsigned int)(t + 1);
            while (load_coh_u32(&flags[tid]) < want)
                __builtin_amdgcn_s_sleep(1);
            asm volatile("" ::: "memory");    // block hoisting next step's loads above poll
            __syncthreads();
        }
    }
}

// ---------------------------------------------------------------------------
extern "C" void kernel_launch(void* const* d_in, const int* in_sizes, int n_in,
                              void* d_out, int out_size, void* d_ws, size_t ws_size,
                              hipStream_t stream) {
    const float* batch   = (const float*)d_in[0];
    const int*   lengths = (const int*)d_in[1];
    const float* c0      = (const float*)d_in[2];
    const float* Wi = (const float*)d_in[3];
    const float* bi = (const float*)d_in[4];
    const float* Wf = (const float*)d_in[5];
    const float* bf = (const float*)d_in[6];
    const float* Wc = (const float*)d_in[7];
    const float* bc = (const float*)d_in[8];
    const float* Wo = (const float*)d_in[9];
    const float* bo = (const float*)d_in[10];
    float* out = (float*)d_out;

    char* ws = (char*)d_ws;
    unsigned int* flags = (unsigned int*)(ws + OFF_FLAGS);
    f16*   hbuf  = (f16*)(ws + OFF_HBUF);
    float* biasp = (float*)(ws + OFF_BIAS);
    f16*   whp   = (f16*)(ws + OFF_WHP);
    f16*   bxp   = (f16*)(ws + OFF_BXP);
    f16*   xw    = (f16*)(ws + OFF_XW);

    prepack_kernel<<<33040, 256, 0, stream>>>(Wi, Wf, Wc, Wo, bi, bf, bc, bo, c0,
                                              whp, bxp, biasp, hbuf, flags);
    gemm_x_kernel<<<dim3(32, 256), 256, 0, stream>>>(batch, bxp, biasp, xw);
    lstm_persist_kernel<<<256, 256, 0, stream>>>(xw, whp, lengths, c0, out, hbuf, flags);
}

// Round 3
// 9395.998 us; speedup vs baseline: 3.3606x; 1.1674x over previous
//
#include <hip/hip_runtime.h>
#include <cstddef>

typedef _Float16 f16;
typedef _Float16 f16x8 __attribute__((ext_vector_type(8)));
typedef _Float16 f16x4 __attribute__((ext_vector_type(4)));
typedef float f32x4 __attribute__((ext_vector_type(4)));

#define T_STEPS 512
#define BATCH   64
#define DD      1024
#define NTOT    4096   // 4 gates * D, n = d*4 + g (g: 0=i,1=f,2=c,3=o)

// ---- workspace layout (bytes), all 4 KiB aligned ----
#define OFF_FLAGS 0ull                             // 256 u32 (barrier epochs)
#define OFF_HBUF  4096ull                          // 2 * 64 * 1024 f16 = 262144 B
#define OFF_BIAS  (OFF_HBUF + 262144ull)           // 4096 f32
#define OFF_WHP   (OFF_BIAS + 16384ull)            // 8 MB
#define OFF_BXP   (OFF_WHP + 8388608ull)           // 8 MB
#define OFF_XW    (OFF_BXP + 8388608ull)           // 32768*4096 f16 = 256 MB

__device__ __forceinline__ float sigm(float x) { return 1.f / (1.f + __expf(-x)); }
__device__ __forceinline__ float tanh_fast(float x) {
    float e = __expf(-2.f * fabsf(x));
    float t = (1.f - e) / (1.f + e);
    return x >= 0.f ? t : -t;
}

// coherent (cross-XCD) primitives: relaxed agent-scope atomics -> sc0 sc1
// write-through/bypass ops hitting the coherent IF cache.
__device__ __forceinline__ unsigned int load_coh_u32(const unsigned int* p) {
    return __hip_atomic_load((unsigned int*)p, __ATOMIC_RELAXED, __HIP_MEMORY_SCOPE_AGENT);
}
__device__ __forceinline__ void store_coh_u16(unsigned short* p, unsigned short v) {
    __hip_atomic_store(p, v, __ATOMIC_RELAXED, __HIP_MEMORY_SCOPE_AGENT);
}
__device__ __forceinline__ void store_coh_u32(unsigned int* p, unsigned int v) {
    __hip_atomic_store(p, v, __ATOMIC_RELAXED, __HIP_MEMORY_SCOPE_AGENT);
}
__device__ __forceinline__ void waitcnt_vm0() {
    asm volatile("s_waitcnt vmcnt(0)" ::: "memory");
}

// ---------------------------------------------------------------------------
// Prepack: weights -> f16 fragment order (B-frag for mfma_f32_16x16x32_f16:
// lane l holds B[k=S*32+(l>>4)*8+jj][n=NT*16+(l&15)] at arr[((NT*32+S)*64+l)*8+jj]).
// ---------------------------------------------------------------------------
__global__ void prepack_kernel(const float* __restrict__ Wi, const float* __restrict__ Wf,
                               const float* __restrict__ Wc, const float* __restrict__ Wo,
                               const float* __restrict__ bi, const float* __restrict__ bf,
                               const float* __restrict__ bc, const float* __restrict__ bo,
                               const float* __restrict__ c0,
                               f16* __restrict__ whp, f16* __restrict__ bxp,
                               float* __restrict__ biasp, f16* __restrict__ hbuf,
                               unsigned int* __restrict__ flags)
{
    unsigned int gid = blockIdx.x * 256u + threadIdx.x;
    if (gid < 256u) flags[gid] = 0u;
    const float* Ww[4] = {Wi, Wf, Wc, Wo};
    if (gid < 8388608u) {
        unsigned int hi = (gid >= 4194304u);      // 0 -> bxp (k 0..1023), 1 -> whp (k 1024..2047)
        unsigned int e  = gid & 4194303u;
        unsigned int jj = e & 7u;
        unsigned int lidx = (e >> 3) & 63u;
        unsigned int S  = (e >> 9) & 31u;
        unsigned int NT = e >> 14;
        unsigned int n  = NT * 16u + (lidx & 15u);
        unsigned int k  = S * 32u + (lidx >> 4) * 8u + jj + (hi ? 1024u : 0u);
        unsigned int g  = n & 3u, d = n >> 2;
        float v = Ww[g][k * 1024u + d];
        (hi ? whp : bxp)[e] = (f16)v;
    } else if (gid < 8392704u) {                  // bias: 4096
        unsigned int n = gid - 8388608u;
        const float* Bb[4] = {bi, bf, bc, bo};
        biasp[n] = Bb[n & 3u][n >> 2];
    } else if (gid < 8458240u) {                  // hbuf[0][b][d] = tanh(c0[d]) : 65536
        unsigned int e2 = gid - 8392704u;
        hbuf[e2] = (f16)tanh_fast(c0[e2 & 1023u]);
    }
}

// ---------------------------------------------------------------------------
// Phase 1: xw[m][n] = batch[m][:1024] @ Wx[:, n] + bias[n]   (f16 out)
// ---------------------------------------------------------------------------
__global__ __launch_bounds__(256) void gemm_x_kernel(
    const float* __restrict__ A, const f16* __restrict__ Bp,
    const float* __restrict__ biasp, f16* __restrict__ xw)
{
    const int tid = threadIdx.x;
    const int w = tid >> 6, l = tid & 63;
    const int lr = l & 15, lq = l >> 4;
    const int n0 = blockIdx.x * 128;
    const int m0 = blockIdx.y * 128;

    f32x4 acc[2][8];
#pragma unroll
    for (int mt = 0; mt < 2; mt++)
#pragma unroll
        for (int nt = 0; nt < 8; nt++) acc[mt][nt] = (f32x4){0.f, 0.f, 0.f, 0.f};

    const float* a0 = A + (size_t)(m0 + 32 * w + lr) * 1024 + lq * 8;
    const f16x8* bp = (const f16x8*)Bp + (size_t)(n0 >> 4) * (32 * 64) + l;

#pragma unroll 2
    for (int s = 0; s < 32; s++) {
        f16x8 af[2];
#pragma unroll
        for (int mt = 0; mt < 2; mt++) {
            const float* ap = a0 + mt * (16 * 1024) + 32 * s;
            float4 v0 = *(const float4*)ap;
            float4 v1 = *(const float4*)(ap + 4);
            f16x8 tt;
            tt[0] = (f16)v0.x; tt[1] = (f16)v0.y; tt[2] = (f16)v0.z; tt[3] = (f16)v0.w;
            tt[4] = (f16)v1.x; tt[5] = (f16)v1.y; tt[6] = (f16)v1.z; tt[7] = (f16)v1.w;
            af[mt] = tt;
        }
#pragma unroll
        for (int nt = 0; nt < 8; nt++) {
            f16x8 bfr = bp[(size_t)(nt * 32 + s) * 64];
            acc[0][nt] = __builtin_amdgcn_mfma_f32_16x16x32_f16(af[0], bfr, acc[0][nt], 0, 0, 0);
            acc[1][nt] = __builtin_amdgcn_mfma_f32_16x16x32_f16(af[1], bfr, acc[1][nt], 0, 0, 0);
        }
    }
#pragma unroll
    for (int nt = 0; nt < 8; nt++) {
        int n = n0 + nt * 16 + lr;
        float bias = biasp[n];
#pragma unroll
        for (int mt = 0; mt < 2; mt++) {
#pragma unroll
            for (int r = 0; r < 4; r++) {
                int m = m0 + 32 * w + mt * 16 + lq * 4 + r;
                xw[(size_t)m * NTOT + n] = (f16)(acc[mt][nt][r] + bias);
            }
        }
    }
}

// ---------------------------------------------------------------------------
// Phase 2: persistent recurrent kernel. 256 WGs x 256 thr, WG j owns gate
// cols [16j,16j+16). Weights in LDS (staged once). h stores: coherent
// write-through. h loads: plain cached loads, made safe by one agent-scope
// acquire fence per step after the flag barrier. Barrier: per-WG epoch flag
// store + all-to-all poll (no RMW).
// ---------------------------------------------------------------------------
__global__ __launch_bounds__(256, 1) void lstm_persist_kernel(
    const f16* __restrict__ xw, const f16* __restrict__ whp,
    const int* __restrict__ lengths, const float* __restrict__ c0,
    float* __restrict__ out, f16* hbuf, unsigned int* flags)
{
    const int j = blockIdx.x;
    const int tid = threadIdx.x;
    const int w = tid >> 6, l = tid & 63;
    const int lr = l & 15, lq = l >> 4;

    __shared__ f16 wlds[32 * 64 * 8];     // 32 KB: weight fragments
    __shared__ float pre_lds[64 * 16];    // 4 KB: pre-activation transpose

    // stage this WG's recurrent-weight fragments into LDS (2048 x 16B)
    {
        const f16x8* wp = (const f16x8*)whp + (size_t)j * 2048;
        f16x8* wl = (f16x8*)wlds;
        for (int i = tid; i < 2048; i += 256) wl[i] = wp[i];
    }
    __syncthreads();

    const int b = tid >> 2, dl = tid & 3;
    float c = c0[4 * j + dl];
    const int len = lengths[b];

    const int rowA = 16 * w + lr;
    const int koff = lq * 8;
    const f16x8* wl = (const f16x8*)wlds + l;   // + s*64 per slice

    for (int t = 0; t < T_STEPS; t++) {
        const int p = t & 1;
        const f16* hb = hbuf + (size_t)p * (BATCH * DD);
        const f16x8* ap = (const f16x8*)(hb + (size_t)rowA * DD + koff);  // + s*4 per slice

        const f16* xwp = xw + (size_t)(t * BATCH + b) * NTOT + 16 * j + 4 * dl;
        f16x4 xg = *(const f16x4*)xwp;

        f32x4 acc0 = {0.f, 0.f, 0.f, 0.f}, acc1 = {0.f, 0.f, 0.f, 0.f};
#pragma unroll
        for (int s = 0; s < 32; s += 2) {
            f16x8 a0 = ap[4 * s];
            f16x8 a1 = ap[4 * (s + 1)];
            f16x8 w0 = wl[64 * s];
            f16x8 w1 = wl[64 * (s + 1)];
            acc0 = __builtin_amdgcn_mfma_f32_16x16x32_f16(a0, w0, acc0, 0, 0, 0);
            acc1 = __builtin_amdgcn_mfma_f32_16x16x32_f16(a1, w1, acc1, 0, 0, 0);
        }
        f32x4 pre = acc0 + acc1;
        // D layout: row = 16w + lq*4 + r (batch), col = lr (n_local)
#pragma unroll
        for (int r = 0; r < 4; r++)
            pre_lds[(16 * w + lq * 4 + r) * 16 + lr] = pre[r];
        __syncthreads();

        float4 g4 = *(const float4*)&pre_lds[b * 16 + 4 * dl];
        float pi = g4.x + (float)xg[0];
        float pf = g4.y + (float)xg[1];
        float pg = g4.z + (float)xg[2];
        float po = g4.w + (float)xg[3];
        float iv = sigm(pi), fv = sigm(pf), gv = tanh_fast(pg), ov = sigm(po);
        c = fv * c + iv * gv;
        float h = ov * tanh_fast(c);
        if (t >= len) h = 0.f;                // mask carried AND emitted h (ref semantics)

        if (t + 1 < T_STEPS) {
            // write-through h for next step (visible at IF coherency point)
            f16 hf = (f16)h;
            store_coh_u16((unsigned short*)(hbuf + (size_t)(p ^ 1) * (BATCH * DD)
                                            + (size_t)b * DD + 4 * j + dl),
                          __builtin_bit_cast(unsigned short, hf));
            waitcnt_vm0();                    // h store reached coherency point
            __syncthreads();                  // whole WG done storing
            if (tid == 0) store_coh_u32(&flags[j], (unsigned int)(t + 1));

            out[(size_t)t * (BATCH * DD) + (size_t)b * DD + 4 * j + dl] = h;  // off critical path

            // all-to-all poll: thread i watches WG i's epoch
            const unsigned int want = (unsigned int)(t + 1);
            while (load_coh_u32(&flags[tid]) < want)
                __builtin_amdgcn_s_sleep(1);
            __syncthreads();                  // all 256 flags observed set
            // invalidate stale L1/L2 h lines before next step's cached loads
            __builtin_amdgcn_fence(__ATOMIC_ACQUIRE, "agent");
            asm volatile("" ::: "memory");
        } else {
            out[(size_t)t * (BATCH * DD) + (size_t)b * DD + 4 * j + dl] = h;
        }
    }
}

// ---------------------------------------------------------------------------
extern "C" void kernel_launch(void* const* d_in, const int* in_sizes, int n_in,
                              void* d_out, int out_size, void* d_ws, size_t ws_size,
                              hipStream_t stream) {
    const float* batch   = (const float*)d_in[0];
    const int*   lengths = (const int*)d_in[1];
    const float* c0      = (const float*)d_in[2];
    const float* Wi = (const float*)d_in[3];
    const float* bi = (const float*)d_in[4];
    const float* Wf = (const float*)d_in[5];
    const float* bf = (const float*)d_in[6];
    const float* Wc = (const float*)d_in[7];
    const float* bc = (const float*)d_in[8];
    const float* Wo = (const float*)d_in[9];
    const float* bo = (const float*)d_in[10];
    float* out = (float*)d_out;

    char* ws = (char*)d_ws;
    unsigned int* flags = (unsigned int*)(ws + OFF_FLAGS);
    f16*   hbuf  = (f16*)(ws + OFF_HBUF);
    float* biasp = (float*)(ws + OFF_BIAS);
    f16*   whp   = (f16*)(ws + OFF_WHP);
    f16*   bxp   = (f16*)(ws + OFF_BXP);
    f16*   xw    = (f16*)(ws + OFF_XW);

    prepack_kernel<<<33040, 256, 0, stream>>>(Wi, Wf, Wc, Wo, bi, bf, bc, bo, c0,
                                              whp, bxp, biasp, hbuf, flags);
    gemm_x_kernel<<<dim3(32, 256), 256, 0, stream>>>(batch, bxp, biasp, xw);
    lstm_persist_kernel<<<256, 256, 0, stream>>>(xw, whp, lengths, c0, out, hbuf, flags);
}